// Round 7
// baseline (518.812 us; speedup 1.0000x reference)
//
#include <hip/hip_runtime.h>
#include <hip/hip_fp16.h>

#define DEG 6
#define RC 10
#define NBATCH 2048
#define FDIM 490
#define KPAD 512
#define HID 4096

typedef _Float16 f16x8 __attribute__((ext_vector_type(8)));
typedef _Float16 f16x2 __attribute__((ext_vector_type(2)));
typedef float f32x4 __attribute__((ext_vector_type(4)));

__device__ inline float dot2f(f16x2 x, f16x2 w, float acc) {
#if __has_builtin(__builtin_amdgcn_fdot2)
    return __builtin_amdgcn_fdot2(x, w, acc, false);
#else
    return acc + (float)x[0] * (float)w[0] + (float)x[1] * (float)w[1];
#endif
}

// ---------------- Wigner coefficient tables (device, each call) --------------
__global__ void coef_kernel(float* __restrict__ Ctab) {
    int p = blockIdx.x * blockDim.x + threadIdx.x;
    if (p >= 455) return;
    const int poff[8] = {0, 1, 10, 35, 84, 165, 286, 455};
    const int loff[7] = {0, 1, 28, 153, 496, 1225, 2556};
    int l = 0;
    while (p >= poff[l + 1]) ++l;
    int idx = p - poff[l];
    int nn = 2 * l + 1;
    int mpi = idx / nn, mi = idx % nn;
    int mp = mpi - l, m = mi - l;
    double f[13];
    f[0] = 1.0;
    for (int i = 1; i < 13; ++i) f[i] = f[i - 1] * i;
    double pref = sqrt(f[l + mp] * f[l - mp] * f[l + m] * f[l - m]);
    float* row = Ctab + loff[l] + (size_t)(mpi * nn + mi) * nn;
    for (int q = 0; q < nn; ++q) row[q] = 0.f;
    int s0 = max(0, m - mp), s1 = min(l + m, l - mp);
    for (int s = s0; s <= s1; ++s) {
        int q = mp - m + 2 * s;
        double den = f[l + m - s] * f[s] * f[mp - m + s] * f[l - mp - s];
        double t = pref / den;
        if ((mp - m + s) & 1) t = -t;
        row[q] += (float)t;
    }
}

// ---------------- Wigner D + item projection -> fp16 item[n][512] ------------
__global__ __launch_bounds__(64) void wigner_kernel(
    const float* __restrict__ angles, const float* __restrict__ item_rep,
    const float* __restrict__ Ctab, __half* __restrict__ item_h) {
    int n = blockIdx.x, lane = threadIdx.x;
    float alpha = angles[n * 3 + 0], beta = angles[n * 3 + 1], gamma = angles[n * 3 + 2];
    float cb = cosf(beta * 0.5f), sb = sinf(beta * 0.5f);
    __shared__ float dsh[169], Dsh[169], Psh[13];
    __shared__ float ear[13], eai[13], egr[13], egi[13];
    const int loff[7] = {0, 1, 28, 153, 496, 1225, 2556};
    const float isq = 0.7071067811865476f;
    for (int l = 0; l <= DEG; ++l) {
        int nn = 2 * l + 1;
        if (lane < nn) {
            int q = lane;
            float pv = 1.f;
            for (int i = 0; i < 2 * l - q; ++i) pv *= cb;
            for (int i = 0; i < q; ++i) pv *= sb;
            Psh[q] = pv;
            float mm = (float)(lane - l);
            float sa, ca; sincosf(alpha * mm, &sa, &ca);
            ear[lane] = ca; eai[lane] = -sa;
            float sg, cg; sincosf(gamma * mm, &sg, &cg);
            egr[lane] = cg; egi[lane] = -sg;
        }
        __syncthreads();
        const float* Cl = Ctab + loff[l];
        for (int e = lane; e < nn * nn; e += 64) {
            float acc = 0.f;
            const float* cr = Cl + e * nn;
            for (int q = 0; q < nn; ++q) acc += cr[q] * Psh[q];
            dsh[e] = acc;
        }
        __syncthreads();
        for (int e = lane; e < nn * nn; e += 64) {
            int u = e / nn, v = e - u * nn;
            int bn, bi0, bi1; float br0, br1, bm0, bm1;
            int mu = u - l;
            if (mu == 0)      { bn = 1; bi0 = l; br0 = 1.f; bm0 = 0.f; bi1 = 0; br1 = 0.f; bm1 = 0.f; }
            else if (mu > 0)  { bn = 2; bi0 = l + mu; br0 = (mu & 1) ? -isq : isq; bm0 = 0.f;
                                bi1 = l - mu; br1 = isq; bm1 = 0.f; }
            else              { int mm2 = -mu; bn = 2; bi0 = l - mm2; br0 = 0.f; bm0 = isq;
                                bi1 = l + mm2; br1 = 0.f; bm1 = (mm2 & 1) ? isq : -isq; }
            int cn, ci0, ci1; float cr0, cr1, cm0, cm1;
            int nu = v - l;
            if (nu == 0)      { cn = 1; ci0 = l; cr0 = 1.f; cm0 = 0.f; ci1 = 0; cr1 = 0.f; cm1 = 0.f; }
            else if (nu > 0)  { cn = 2; ci0 = l + nu; cr0 = (nu & 1) ? -isq : isq; cm0 = 0.f;
                                ci1 = l - nu; cr1 = isq; cm1 = 0.f; }
            else              { int mm2 = -nu; cn = 2; ci0 = l - mm2; cr0 = 0.f; cm0 = -isq;
                                ci1 = l + mm2; cr1 = 0.f; cm1 = (mm2 & 1) ? -isq : isq; }
            float acc = 0.f;
            #pragma unroll
            for (int pb = 0; pb < 2; ++pb) {
                if (pb >= bn) break;
                int b = pb ? bi1 : bi0;
                float sr = pb ? br1 : br0, si = pb ? bm1 : bm0;
                float z1r = sr * ear[b] - si * eai[b];
                float z1i = sr * eai[b] + si * ear[b];
                #pragma unroll
                for (int pc = 0; pc < 2; ++pc) {
                    if (pc >= cn) break;
                    int c = pc ? ci1 : ci0;
                    float tr = pc ? cr1 : cr0, ti = pc ? cm1 : cm0;
                    float dv = dsh[b * nn + c];
                    float z2r = egr[c] * tr - egi[c] * ti;
                    float z2i = egr[c] * ti + egi[c] * tr;
                    acc += dv * (z1r * z2r - z1i * z2i);
                }
            }
            Dsh[e] = acc;
        }
        __syncthreads();
        for (int e = lane; e < nn * RC; e += 64) {
            int u = e / RC, r = e - u * RC;
            float acc = 0.f;
            for (int v = 0; v < nn; ++v)
                acc += Dsh[u * nn + v] * item_rep[(l * l + v) * RC + r];
            item_h[(size_t)n * KPAD + (l * l + u) * RC + r] = __float2half(acc);
        }
        __syncthreads();
    }
    if (lane < KPAD - FDIM)
        item_h[(size_t)n * KPAD + FDIM + lane] = __float2half(0.f);
}

// ------- FC weight prep (tiled transpose): W[490,4096] f32 -> Wt[4096][512] f16
__global__ __launch_bounds__(256) void fcw_prep2(const float* __restrict__ W,
                                                 __half* __restrict__ Wt) {
    __shared__ _Float16 tile[64][72];
    int k0 = blockIdx.x * 64;
    int o0 = blockIdx.y * 64;
    int tid = threadIdx.x;
    int tx = tid & 63, ty = tid >> 6;
    #pragma unroll
    for (int i = 0; i < 16; ++i) {
        int k = k0 + ty + i * 4;
        float v = (k < FDIM) ? W[(size_t)k * HID + o0 + tx] : 0.f;
        tile[ty + i * 4][tx] = (_Float16)v;
    }
    __syncthreads();
    #pragma unroll
    for (int p = 0; p < 2; ++p) {
        int idx = tid + p * 256;
        int ol = idx >> 3;
        int kl = (idx & 7) * 8;
        f16x8 v;
        #pragma unroll
        for (int e = 0; e < 8; ++e) v[e] = tile[kl + e][ol];
        *(f16x8*)(Wt + (size_t)(o0 + ol) * KPAD + k0 + kl) = v;
    }
}

// ---- conv weight prep: K[4][4][CIN][COUT] f32 -> Bt[par][COUT][4*CIN] f16 ---
template <int CIN, int COUT>
__global__ __launch_bounds__(256) void convw_prep(const float* __restrict__ K,
                                                  __half* __restrict__ Bt) {
    int par = blockIdx.x >> 2, tap = blockIdx.x & 3;
    int pi = par & 1, pj = par >> 1;
    int t1 = tap >> 1, t2 = tap & 1;
    int dh = pi + 2 * t1, dw = pj + 2 * t2;
    const float* Ks = K + (size_t)(dh * 4 + dw) * CIN * COUT;
    int o = threadIdx.x % COUT;
    int cg = threadIdx.x / COUT;
    constexpr int NG = 256 / COUT;
    for (int c0 = cg * 8; c0 < CIN; c0 += NG * 8) {
        f16x8 v;
        #pragma unroll
        for (int e = 0; e < 8; ++e) v[e] = (_Float16)Ks[(size_t)(c0 + e) * COUT + o];
        *(f16x8*)(Bt + ((size_t)par * COUT + o) * (4 * CIN) + tap * CIN + c0) = v;
    }
}

// ---- conv4 weight prep: K[4][4][32][1] f32 -> f16 [16][32] ------------------
__global__ __launch_bounds__(256) void conv4w_prep(const float* __restrict__ K,
                                                   __half* __restrict__ Kh) {
    int t = blockIdx.x * blockDim.x + threadIdx.x;
    if (t < 512) Kh[t] = __float2half(K[t]);
}

// ---------------- FC as MFMA GEMM: [2048x512] x [512x4096] + relu -> f16 -----
__global__ __launch_bounds__(256) void fc_mfma(
    const __half* __restrict__ A, const __half* __restrict__ Wt,
    const float* __restrict__ bias, __half* __restrict__ Y) {
    int lane = threadIdx.x & 63, wid = threadIdx.x >> 6;
    int job = blockIdx.x * 4 + wid;
    int mbase = job * 32;
    int cb = blockIdx.y * 128;
    int klane = (lane >> 4) * 8, coll = lane & 15;
    const __half* pA0 = A + (size_t)(mbase + coll) * KPAD + klane;
    const __half* pB0 = Wt + (size_t)(cb + coll) * KPAD + klane;
    f32x4 acc[2][8] = {};
    for (int s = 0; s < 16; ++s) {
        f16x8 a0 = *(const f16x8*)(pA0 + s * 32);
        f16x8 a1 = *(const f16x8*)(pA0 + 16 * KPAD + s * 32);
        #pragma unroll
        for (int f = 0; f < 8; ++f) {
            f16x8 b = *(const f16x8*)(pB0 + (size_t)f * 16 * KPAD + s * 32);
            acc[0][f] = __builtin_amdgcn_mfma_f32_16x16x32_f16(a0, b, acc[0][f], 0, 0, 0);
            acc[1][f] = __builtin_amdgcn_mfma_f32_16x16x32_f16(a1, b, acc[1][f], 0, 0, 0);
        }
    }
    #pragma unroll
    for (int f = 0; f < 8; ++f) {
        float bv = bias[cb + f * 16 + coll];
        #pragma unroll
        for (int r = 0; r < 2; ++r)
            #pragma unroll
            for (int g = 0; g < 4; ++g) {
                int m = mbase + r * 16 + (lane >> 4) * 4 + g;
                float v = acc[r][f][g] + bv;
                v = v > 0.f ? v : 0.f;
                Y[(size_t)m * HID + cb + f * 16 + coll] = __float2half(v);
            }
    }
}

// ------- conv_transpose: A in LDS (padded stride), B from L2, serial parity --
// LDS row stride = CIN+8 halves -> bank-group (row+slot)%8: every consecutive
// lane octet hits distinct groups (conflict-free reads AND staging writes).
// acc[R][CF] only (parity loop serial); ONE barrier per kernel (after staging).
template <int CIN, int COUT, int HIN, int R, int LOGH, int CF, int WAVES, int CHG, int OH, int OB>
__global__ __launch_bounds__(WAVES * 64) void convt_lds2(
    const __half* __restrict__ X, const __half* __restrict__ Bt,
    const float* __restrict__ bias, __half* __restrict__ Y) {
    constexpr int HH = HIN * HIN;
    constexpr int KTOT = 4 * CIN;
    constexpr int NSTEP = CIN / 32;
    constexpr int SL = CIN / 8;            // 16B slots per row
    constexpr int STR = CIN + 8;           // padded LDS row stride (halves)
    constexpr int T = WAVES * 64;
    constexpr int POSG = WAVES / CHG;      // position groups per block
    constexpr int POS = POSG * R * 16;     // positions (= A rows) per block
    constexpr int AROWS = POS;
    constexpr int SA = AROWS * SL;
    __shared__ _Float16 lds[AROWS * STR];

    int tid = threadIdx.x;
    int lane = tid & 63, w = tid >> 6;
    int kg = lane >> 4, coll = lane & 15;
    int pg = w / CHG, cg = w % CHG;
    int n0 = blockIdx.x * (POS >> (2 * LOGH));
    int cbase = cg * (CF * 16);
    int posbase = pg * (R * 16);

    // ---- stage A (coalesced global, padded LDS) ----
    const __half* Xs = X + (size_t)n0 * HH * CIN;
    #pragma unroll
    for (int q = 0; q < SA / T; ++q) {
        int i = tid + q * T;
        int row = i / SL, slot = i & (SL - 1);
        f16x8 v = *(const f16x8*)(Xs + (size_t)i * 8);
        *(f16x8*)(&lds[row * STR + slot * 8]) = v;
    }
    __syncthreads();

    int posl[R]; bool okr[R][3], okc[R][3];
    #pragma unroll
    for (int r = 0; r < R; ++r) {
        int p = posbase + r * 16 + coll;
        posl[r] = p;
        int rem = p & (HH - 1);
        int a = rem >> LOGH, b = rem & (HIN - 1);
        #pragma unroll
        for (int s = 0; s < 3; ++s) {
            okr[r][s] = (unsigned)(a + s - 1) < (unsigned)HIN;
            okc[r][s] = (unsigned)(b + s - 1) < (unsigned)HIN;
        }
    }

    float bvv[CF];
    #pragma unroll
    for (int f = 0; f < CF; ++f) bvv[f] = bias[cbase + f * 16 + coll];

    #pragma unroll
    for (int par = 0; par < 4; ++par) {
        const int pi = par & 1, pj = par >> 1;
        f32x4 acc[R][CF];
        #pragma unroll
        for (int r = 0; r < R; ++r)
            #pragma unroll
            for (int f = 0; f < CF; ++f)
                acc[r][f] = (f32x4){bvv[f], bvv[f], bvv[f], bvv[f]};

        #pragma unroll
        for (int tap = 0; tap < 4; ++tap) {
            const int iu = (tap >> 1) + pi, iv = (tap & 1) + pj;   // 0..2
            const int delta = (iu - 1) * HIN + (iv - 1);
            int rp[R]; bool ok[R];
            #pragma unroll
            for (int r = 0; r < R; ++r) {
                int t = posl[r] + delta;
                rp[r] = min(max(t, 0), AROWS - 1);
                ok[r] = okr[r][iu] && okc[r][iv];
            }
            const __half* Bp = Bt + ((size_t)(par * COUT + cbase + coll) * KTOT +
                                     tap * CIN + kg * 8);
            #pragma unroll
            for (int cc = 0; cc < NSTEP; ++cc) {
                f16x8 b[CF];
                #pragma unroll
                for (int f = 0; f < CF; ++f)
                    b[f] = *(const f16x8*)(Bp + (size_t)f * 16 * KTOT + cc * 32);
                f16x8 a[R];
                #pragma unroll
                for (int r = 0; r < R; ++r) {
                    f16x8 v = *(const f16x8*)(&lds[rp[r] * STR + (cc * 4 + kg) * 8]);
                    a[r] = ok[r] ? v : (f16x8){0, 0, 0, 0, 0, 0, 0, 0};
                }
                #pragma unroll
                for (int r = 0; r < R; ++r)
                    #pragma unroll
                    for (int f = 0; f < CF; ++f)
                        acc[r][f] = __builtin_amdgcn_mfma_f32_16x16x32_f16(
                            a[r], b[f], acc[r][f], 0, 0, 0);
            }
        }

        // ---- epilogue for this parity ----
        #pragma unroll
        for (int r = 0; r < R; ++r) {
            #pragma unroll
            for (int g = 0; g < 4; ++g) {
                int p = posbase + r * 16 + kg * 4 + g;
                int ni = p >> (2 * LOGH);
                int rem = p & (HH - 1);
                int a2 = rem >> LOGH, b2 = rem & (HIN - 1);
                size_t ob = (((size_t)(n0 + ni) * OH + 2 * a2 + pi + OB) * OH +
                             2 * b2 + pj + OB) * COUT;
                #pragma unroll
                for (int f = 0; f < CF; ++f) {
                    float v = acc[r][f][g];
                    v = v > 0.f ? v : 0.f;
                    Y[ob + cbase + f * 16 + coll] = __float2half(v);
                }
            }
        }
    }
}

// ---------------- zero the 1-wide border ring of padded x3 -------------------
__global__ __launch_bounds__(256) void pad_zero(__half* __restrict__ Xp) {
    int n = blockIdx.x;
    __half* base = Xp + (size_t)n * 34 * 34 * 32;
    for (int w = threadIdx.x; w < 132 * 4; w += 256) {
        int posi = w >> 2, q = w & 3;
        int r, s;
        if (posi < 68) { r = (posi < 34) ? 0 : 33; s = posi % 34; }
        else { int e = posi - 68; r = 1 + (e >> 1); s = (e & 1) ? 33 : 0; }
        *(f16x8*)(base + ((size_t)r * 34 + s) * 32 + q * 8) = (f16x8){0, 0, 0, 0, 0, 0, 0, 0};
    }
}

// ---------------- conv4: padded 34x34x32 -> 64x64x1, fp32 out ----------------
__global__ __launch_bounds__(256) void conv4_kernel2(
    const __half* __restrict__ Xp, const __half* __restrict__ Wh,
    const float* __restrict__ bias, float* __restrict__ out) {
    int n = blockIdx.x;
    int t = threadIdx.x;
    int b = t & 31;
    int a = (blockIdx.y << 3) + (t >> 5);
    const __half* Xn = Xp + (size_t)n * 34 * 34 * 32;
    const f16x2* W2 = (const f16x2*)Wh;
    float a00 = 0.f, a01 = 0.f, a10 = 0.f, a11 = 0.f;
    #pragma unroll
    for (int hf = 0; hf < 2; ++hf) {
        f16x2 xw[9][8];
        #pragma unroll
        for (int u = 0; u < 3; ++u)
            #pragma unroll
            for (int v = 0; v < 3; ++v) {
                const f16x8* p = (const f16x8*)(Xn + ((size_t)(a + u) * 34 + (b + v)) * 32 + hf * 16);
                f16x8 lo = p[0], hi = p[1];
                #pragma unroll
                for (int e = 0; e < 4; ++e) {
                    xw[u * 3 + v][e]     = (f16x2){lo[2 * e], lo[2 * e + 1]};
                    xw[u * 3 + v][e + 4] = (f16x2){hi[2 * e], hi[2 * e + 1]};
                }
            }
        #pragma unroll
        for (int pi = 0; pi < 2; ++pi)
            #pragma unroll
            for (int pj = 0; pj < 2; ++pj) {
                float acc = pi ? (pj ? a11 : a10) : (pj ? a01 : a00);
                #pragma unroll
                for (int t1 = 0; t1 < 2; ++t1)
                    #pragma unroll
                    for (int t2 = 0; t2 < 2; ++t2) {
                        int pos = (pi + t1) * 3 + (pj + t2);
                        const f16x2* wrow = W2 + ((pi + 2 * t1) * 4 + (pj + 2 * t2)) * 16 + hf * 8;
                        #pragma unroll
                        for (int e = 0; e < 8; ++e)
                            acc = dot2f(xw[pos][e], wrow[e], acc);
                    }
                if (pi) { if (pj) a11 = acc; else a10 = acc; }
                else    { if (pj) a01 = acc; else a00 = acc; }
            }
    }
    float bv = bias[0];
    out[((size_t)n * 64 + 2 * a + 0) * 64 + 2 * b + 0] = a00 + bv;
    out[((size_t)n * 64 + 2 * a + 0) * 64 + 2 * b + 1] = a01 + bv;
    out[((size_t)n * 64 + 2 * a + 1) * 64 + 2 * b + 0] = a10 + bv;
    out[((size_t)n * 64 + 2 * a + 1) * 64 + 2 * b + 1] = a11 + bv;
}

// ---------------- launch -----------------------------------------------------
extern "C" void kernel_launch(void* const* d_in, const int* in_sizes, int n_in,
                              void* d_out, int out_size, void* d_ws, size_t ws_size,
                              hipStream_t stream) {
    const float* angles   = (const float*)d_in[0];
    const float* item_rep = (const float*)d_in[1];
    const float* W        = (const float*)d_in[2];
    const float* bfc      = (const float*)d_in[3];
    const float* k1       = (const float*)d_in[4];
    const float* b1       = (const float*)d_in[5];
    const float* k2       = (const float*)d_in[6];
    const float* b2       = (const float*)d_in[7];
    const float* k3       = (const float*)d_in[8];
    const float* b3       = (const float*)d_in[9];
    const float* k4       = (const float*)d_in[10];
    const float* b4       = (const float*)d_in[11];

    char* ws = (char*)d_ws;
    float*  Ctab  = (float*)(ws + 0);                 //  32 KB
    __half* itemh = (__half*)(ws + 32768);            //   2 MB
    __half* Bt1   = (__half*)(ws + 2129920);          //   1 MB
    __half* Bt2   = (__half*)(ws + 3178496);          // 256 KB
    __half* Bt3   = (__half*)(ws + 3440640);          //  64 KB
    __half* Kh4   = (__half*)(ws + 3506176);          //   1 KB
    __half* x0    = (__half*)(ws + 4194304);          //  16 MB -> 20,971,520
    __half* x1    = (__half*)(ws + 20971520);         //  32 MB -> 54,525,952
    __half* x3p   = (__half*)(ws + 4194304);          // 151.5 MB -> 155,713,536
    __half* Wtfc  = (__half*)(ws + 121634816);        //   4 MB (inside x3p, dead by conv3)
    __half* x2    = (__half*)(ws + 155713536);        //  64 MB -> 222,822,400
    float*  out   = (float*)d_out;

    coef_kernel<<<1, 512, 0, stream>>>(Ctab);
    wigner_kernel<<<NBATCH, 64, 0, stream>>>(angles, item_rep, Ctab, itemh);
    fcw_prep2<<<dim3(KPAD / 64, HID / 64), 256, 0, stream>>>(W, Wtfc);
    convw_prep<256, 128><<<16, 256, 0, stream>>>(k1, Bt1);
    convw_prep<128, 64><<<16, 256, 0, stream>>>(k2, Bt2);
    convw_prep<64, 32><<<16, 256, 0, stream>>>(k3, Bt3);
    conv4w_prep<<<2, 256, 0, stream>>>(k4, Kh4);

    // FC: 2048x512 @ 512x4096 -> x0
    fc_mfma<<<dim3(16, 32), 256, 0, stream>>>(itemh, Wtfc, bfc, x0);
    // conv1: 4x4x256 -> 8x8x128  (R=2, CF=4, 2 ch-groups; 4 images/block)
    convt_lds2<256, 128, 4, 2, 2, 4, 4, 2, 8, 0><<<512, 256, 0, stream>>>(x0, Bt1, b1, x1);
    // conv2: 8x8x128 -> 16x16x64 (R=2, CF=4; 2 images/block)
    convt_lds2<128, 64, 8, 2, 3, 4, 4, 1, 16, 0><<<1024, 256, 0, stream>>>(x1, Bt2, b2, x2);
    // zero x3p border ring, then conv3 writes the 32x32 interior at +1
    pad_zero<<<NBATCH, 256, 0, stream>>>(x3p);
    // conv3: 16x16x64 -> (34x34 padded)x32 (R=4, CF=2; 1 image/block)
    convt_lds2<64, 32, 16, 4, 4, 2, 4, 1, 34, 1><<<2048, 256, 0, stream>>>(x2, Bt3, b3, x3p);
    // conv4: padded 34x34x32 -> 64x64x1 (fp32 out)
    conv4_kernel2<<<dim3(NBATCH, 4), 256, 0, stream>>>(x3p, Kh4, b4, out);
}

// Round 8
// 350.493 us; speedup vs baseline: 1.4802x; 1.4802x over previous
//
#include <hip/hip_runtime.h>
#include <hip/hip_fp16.h>

#define DEG 6
#define RC 10
#define NBATCH 2048
#define FDIM 490
#define KPAD 512
#define HID 4096

typedef _Float16 f16x8 __attribute__((ext_vector_type(8)));
typedef _Float16 f16x2 __attribute__((ext_vector_type(2)));
typedef float f32x4 __attribute__((ext_vector_type(4)));

__device__ inline float dot2f(f16x2 x, f16x2 w, float acc) {
#if __has_builtin(__builtin_amdgcn_fdot2)
    return __builtin_amdgcn_fdot2(x, w, acc, false);
#else
    return acc + (float)x[0] * (float)w[0] + (float)x[1] * (float)w[1];
#endif
}

// ---------------- Wigner coefficient tables (device, each call) --------------
__global__ void coef_kernel(float* __restrict__ Ctab) {
    int p = blockIdx.x * blockDim.x + threadIdx.x;
    if (p >= 455) return;
    const int poff[8] = {0, 1, 10, 35, 84, 165, 286, 455};
    const int loff[7] = {0, 1, 28, 153, 496, 1225, 2556};
    int l = 0;
    while (p >= poff[l + 1]) ++l;
    int idx = p - poff[l];
    int nn = 2 * l + 1;
    int mpi = idx / nn, mi = idx % nn;
    int mp = mpi - l, m = mi - l;
    double f[13];
    f[0] = 1.0;
    for (int i = 1; i < 13; ++i) f[i] = f[i - 1] * i;
    double pref = sqrt(f[l + mp] * f[l - mp] * f[l + m] * f[l - m]);
    float* row = Ctab + loff[l] + (size_t)(mpi * nn + mi) * nn;
    for (int q = 0; q < nn; ++q) row[q] = 0.f;
    int s0 = max(0, m - mp), s1 = min(l + m, l - mp);
    for (int s = s0; s <= s1; ++s) {
        int q = mp - m + 2 * s;
        double den = f[l + m - s] * f[s] * f[mp - m + s] * f[l - mp - s];
        double t = pref / den;
        if ((mp - m + s) & 1) t = -t;
        row[q] += (float)t;
    }
}

// ---------------- Wigner D + item projection -> fp16 item[n][512] ------------
__global__ __launch_bounds__(64) void wigner_kernel(
    const float* __restrict__ angles, const float* __restrict__ item_rep,
    const float* __restrict__ Ctab, __half* __restrict__ item_h) {
    int n = blockIdx.x, lane = threadIdx.x;
    float alpha = angles[n * 3 + 0], beta = angles[n * 3 + 1], gamma = angles[n * 3 + 2];
    float cb = cosf(beta * 0.5f), sb = sinf(beta * 0.5f);
    __shared__ float dsh[169], Dsh[169], Psh[13];
    __shared__ float ear[13], eai[13], egr[13], egi[13];
    const int loff[7] = {0, 1, 28, 153, 496, 1225, 2556};
    const float isq = 0.7071067811865476f;
    for (int l = 0; l <= DEG; ++l) {
        int nn = 2 * l + 1;
        if (lane < nn) {
            int q = lane;
            float pv = 1.f;
            for (int i = 0; i < 2 * l - q; ++i) pv *= cb;
            for (int i = 0; i < q; ++i) pv *= sb;
            Psh[q] = pv;
            float mm = (float)(lane - l);
            float sa, ca; sincosf(alpha * mm, &sa, &ca);
            ear[lane] = ca; eai[lane] = -sa;
            float sg, cg; sincosf(gamma * mm, &sg, &cg);
            egr[lane] = cg; egi[lane] = -sg;
        }
        __syncthreads();
        const float* Cl = Ctab + loff[l];
        for (int e = lane; e < nn * nn; e += 64) {
            float acc = 0.f;
            const float* cr = Cl + e * nn;
            for (int q = 0; q < nn; ++q) acc += cr[q] * Psh[q];
            dsh[e] = acc;
        }
        __syncthreads();
        for (int e = lane; e < nn * nn; e += 64) {
            int u = e / nn, v = e - u * nn;
            int bn, bi0, bi1; float br0, br1, bm0, bm1;
            int mu = u - l;
            if (mu == 0)      { bn = 1; bi0 = l; br0 = 1.f; bm0 = 0.f; bi1 = 0; br1 = 0.f; bm1 = 0.f; }
            else if (mu > 0)  { bn = 2; bi0 = l + mu; br0 = (mu & 1) ? -isq : isq; bm0 = 0.f;
                                bi1 = l - mu; br1 = isq; bm1 = 0.f; }
            else              { int mm2 = -mu; bn = 2; bi0 = l - mm2; br0 = 0.f; bm0 = isq;
                                bi1 = l + mm2; br1 = 0.f; bm1 = (mm2 & 1) ? isq : -isq; }
            int cn, ci0, ci1; float cr0, cr1, cm0, cm1;
            int nu = v - l;
            if (nu == 0)      { cn = 1; ci0 = l; cr0 = 1.f; cm0 = 0.f; ci1 = 0; cr1 = 0.f; cm1 = 0.f; }
            else if (nu > 0)  { cn = 2; ci0 = l + nu; cr0 = (nu & 1) ? -isq : isq; cm0 = 0.f;
                                ci1 = l - nu; cr1 = isq; cm1 = 0.f; }
            else              { int mm2 = -nu; cn = 2; ci0 = l - mm2; cr0 = 0.f; cm0 = -isq;
                                ci1 = l + mm2; cr1 = 0.f; cm1 = (mm2 & 1) ? -isq : isq; }
            float acc = 0.f;
            #pragma unroll
            for (int pb = 0; pb < 2; ++pb) {
                if (pb >= bn) break;
                int b = pb ? bi1 : bi0;
                float sr = pb ? br1 : br0, si = pb ? bm1 : bm0;
                float z1r = sr * ear[b] - si * eai[b];
                float z1i = sr * eai[b] + si * ear[b];
                #pragma unroll
                for (int pc = 0; pc < 2; ++pc) {
                    if (pc >= cn) break;
                    int c = pc ? ci1 : ci0;
                    float tr = pc ? cr1 : cr0, ti = pc ? cm1 : cm0;
                    float dv = dsh[b * nn + c];
                    float z2r = egr[c] * tr - egi[c] * ti;
                    float z2i = egr[c] * ti + egi[c] * tr;
                    acc += dv * (z1r * z2r - z1i * z2i);
                }
            }
            Dsh[e] = acc;
        }
        __syncthreads();
        for (int e = lane; e < nn * RC; e += 64) {
            int u = e / RC, r = e - u * RC;
            float acc = 0.f;
            for (int v = 0; v < nn; ++v)
                acc += Dsh[u * nn + v] * item_rep[(l * l + v) * RC + r];
            item_h[(size_t)n * KPAD + (l * l + u) * RC + r] = __float2half(acc);
        }
        __syncthreads();
    }
    if (lane < KPAD - FDIM)
        item_h[(size_t)n * KPAD + FDIM + lane] = __float2half(0.f);
}

// ------- FC weight prep (tiled transpose): W[490,4096] f32 -> Wt[4096][512] f16
__global__ __launch_bounds__(256) void fcw_prep2(const float* __restrict__ W,
                                                 __half* __restrict__ Wt) {
    __shared__ _Float16 tile[64][72];
    int k0 = blockIdx.x * 64;
    int o0 = blockIdx.y * 64;
    int tid = threadIdx.x;
    int tx = tid & 63, ty = tid >> 6;
    #pragma unroll
    for (int i = 0; i < 16; ++i) {
        int k = k0 + ty + i * 4;
        float v = (k < FDIM) ? W[(size_t)k * HID + o0 + tx] : 0.f;
        tile[ty + i * 4][tx] = (_Float16)v;
    }
    __syncthreads();
    #pragma unroll
    for (int p = 0; p < 2; ++p) {
        int idx = tid + p * 256;
        int ol = idx >> 3;
        int kl = (idx & 7) * 8;
        f16x8 v;
        #pragma unroll
        for (int e = 0; e < 8; ++e) v[e] = tile[kl + e][ol];
        *(f16x8*)(Wt + (size_t)(o0 + ol) * KPAD + k0 + kl) = v;
    }
}

// ---- conv weight prep: K[4][4][CIN][COUT] f32 -> Bt[par][COUT][4*CIN] f16 ---
template <int CIN, int COUT>
__global__ __launch_bounds__(256) void convw_prep(const float* __restrict__ K,
                                                  __half* __restrict__ Bt) {
    int par = blockIdx.x >> 2, tap = blockIdx.x & 3;
    int pi = par & 1, pj = par >> 1;
    int t1 = tap >> 1, t2 = tap & 1;
    int dh = pi + 2 * t1, dw = pj + 2 * t2;
    const float* Ks = K + (size_t)(dh * 4 + dw) * CIN * COUT;
    int o = threadIdx.x % COUT;
    int cg = threadIdx.x / COUT;
    constexpr int NG = 256 / COUT;
    for (int c0 = cg * 8; c0 < CIN; c0 += NG * 8) {
        f16x8 v;
        #pragma unroll
        for (int e = 0; e < 8; ++e) v[e] = (_Float16)Ks[(size_t)(c0 + e) * COUT + o];
        *(f16x8*)(Bt + ((size_t)par * COUT + o) * (4 * CIN) + tap * CIN + c0) = v;
    }
}

// ---- conv4 weight prep: K[4][4][32][1] f32 -> f16 [16][32] ------------------
__global__ __launch_bounds__(256) void conv4w_prep(const float* __restrict__ K,
                                                   __half* __restrict__ Kh) {
    int t = blockIdx.x * blockDim.x + threadIdx.x;
    if (t < 512) Kh[t] = __float2half(K[t]);
}

// ---------------- FC as MFMA GEMM: [2048x512] x [512x4096] + relu -> f16 -----
__global__ __launch_bounds__(256) void fc_mfma(
    const __half* __restrict__ A, const __half* __restrict__ Wt,
    const float* __restrict__ bias, __half* __restrict__ Y) {
    int lane = threadIdx.x & 63, wid = threadIdx.x >> 6;
    int job = blockIdx.x * 4 + wid;
    int mbase = job * 32;
    int cb = blockIdx.y * 128;
    int klane = (lane >> 4) * 8, coll = lane & 15;
    const __half* pA0 = A + (size_t)(mbase + coll) * KPAD + klane;
    const __half* pB0 = Wt + (size_t)(cb + coll) * KPAD + klane;
    f32x4 acc[2][8] = {};
    for (int s = 0; s < 16; ++s) {
        f16x8 a0 = *(const f16x8*)(pA0 + s * 32);
        f16x8 a1 = *(const f16x8*)(pA0 + 16 * KPAD + s * 32);
        #pragma unroll
        for (int f = 0; f < 8; ++f) {
            f16x8 b = *(const f16x8*)(pB0 + (size_t)f * 16 * KPAD + s * 32);
            acc[0][f] = __builtin_amdgcn_mfma_f32_16x16x32_f16(a0, b, acc[0][f], 0, 0, 0);
            acc[1][f] = __builtin_amdgcn_mfma_f32_16x16x32_f16(a1, b, acc[1][f], 0, 0, 0);
        }
    }
    #pragma unroll
    for (int f = 0; f < 8; ++f) {
        float bv = bias[cb + f * 16 + coll];
        #pragma unroll
        for (int r = 0; r < 2; ++r)
            #pragma unroll
            for (int g = 0; g < 4; ++g) {
                int m = mbase + r * 16 + (lane >> 4) * 4 + g;
                float v = acc[r][f][g] + bv;
                v = v > 0.f ? v : 0.f;
                Y[(size_t)m * HID + cb + f * 16 + coll] = __float2half(v);
            }
    }
}

// ------- conv_transpose: A + double-buffered B both in LDS, serial parity ----
// XOR swizzle slot^=(row&7) on BOTH write and read sides (row-stride dwords
// ≡ 0 mod 32 -> 16 consecutive-row lanes spread 8 slot-groups x 4 banks = 2-way,
// free). B staged per (par,tap[,k-half]) coalesced w/ issue-early/write-late;
// ONE barrier per stage. acc[R][CF] only (parity serial).
template <int CIN, int COUT, int HIN, int R, int LOGH, int CF, int WAVES, int KSPLIT, int OH, int OB>
__global__ __launch_bounds__(WAVES * 64) void convt_lds3(
    const __half* __restrict__ X, const __half* __restrict__ Bt,
    const float* __restrict__ bias, __half* __restrict__ Y) {
    constexpr int HH = HIN * HIN;
    constexpr int KTOT = 4 * CIN;
    constexpr int CINS = CIN / KSPLIT;     // k-width per stage
    constexpr int NSTEPS = CINS / 32;      // k-chunks per stage
    constexpr int SL = CIN / 8;            // A 16B slots per row
    constexpr int SLB = CINS / 8;          // B 16B slots per row
    constexpr int T = WAVES * 64;
    constexpr int POS = WAVES * R * 16;    // positions (= A rows) per block
    constexpr int AROWS = POS;
    constexpr int AH = AROWS * CIN;        // halves
    constexpr int BROWS = CF * 16;
    constexpr int BH = BROWS * CINS;       // halves per B buffer
    constexpr int SA = AROWS * SL;
    constexpr int SB = BROWS * SLB;
    constexpr int NSB = SB / T;
    constexpr int NST = 16 * KSPLIT;       // total stages
    __shared__ _Float16 lds[AH + 2 * BH];

    int tid = threadIdx.x;
    int lane = tid & 63, w = tid >> 6;
    int kg = lane >> 4, coll = lane & 15;
    int n0 = blockIdx.x * (POS >> (2 * LOGH));
    int cbase = blockIdx.y * (CF * 16);
    int posbase = w * (R * 16);

    // ---- stage A (coalesced global -> swizzled LDS) ----
    const __half* Xs = X + (size_t)n0 * HH * CIN;
    #pragma unroll
    for (int q = 0; q < SA / T; ++q) {
        int i = tid + q * T;
        int row = i / SL, slot = i % SL;
        f16x8 v = *(const f16x8*)(Xs + (size_t)i * 8);
        *(f16x8*)(&lds[row * CIN + ((slot ^ (row & 7)) * 8)]) = v;
    }
    // ---- stage B for stage 0 into buffer 0 ----
    f16x8 breg[NSB];
    #pragma unroll
    for (int q = 0; q < NSB; ++q) {
        int i = tid + q * T;
        int o = i / SLB, sl = i % SLB;
        breg[q] = *(const f16x8*)(Bt + ((size_t)(cbase + o) * KTOT) + sl * 8);
    }
    #pragma unroll
    for (int q = 0; q < NSB; ++q) {
        int i = tid + q * T;
        int o = i / SLB, sl = i % SLB;
        *(f16x8*)(&lds[AH + o * CINS + ((sl ^ (o & 7)) * 8)]) = breg[q];
    }
    __syncthreads();

    int posl[R]; bool okr[R][3], okc[R][3];
    #pragma unroll
    for (int r = 0; r < R; ++r) {
        int p = posbase + r * 16 + coll;
        posl[r] = p;
        int rem = p & (HH - 1);
        int a = rem >> LOGH, b = rem & (HIN - 1);
        #pragma unroll
        for (int s = 0; s < 3; ++s) {
            okr[r][s] = (unsigned)(a + s - 1) < (unsigned)HIN;
            okc[r][s] = (unsigned)(b + s - 1) < (unsigned)HIN;
        }
    }

    float bvv[CF];
    #pragma unroll
    for (int f = 0; f < CF; ++f) bvv[f] = bias[cbase + f * 16 + coll];

    #pragma unroll
    for (int par = 0; par < 4; ++par) {
        const int pi = par & 1, pj = par >> 1;
        f32x4 acc[R][CF];
        #pragma unroll
        for (int r = 0; r < R; ++r)
            #pragma unroll
            for (int f = 0; f < CF; ++f)
                acc[r][f] = (f32x4){bvv[f], bvv[f], bvv[f], bvv[f]};

        #pragma unroll
        for (int tt = 0; tt < 4 * KSPLIT; ++tt) {
            const int s = par * 4 * KSPLIT + tt;
            const int tap = tt / KSPLIT;
            const int kh = tt % KSPLIT;
            const int buf = s & 1;
            // issue next stage's B loads early (hide HBM/L2 latency under MFMA)
            if (s + 1 < NST) {
                const int s2 = s + 1;
                const int par2 = s2 / (4 * KSPLIT);
                const int tt2 = s2 % (4 * KSPLIT);
                const int tap2 = tt2 / KSPLIT;
                const int kh2 = tt2 % KSPLIT;
                #pragma unroll
                for (int q = 0; q < NSB; ++q) {
                    int i = tid + q * T;
                    int o = i / SLB, sl = i % SLB;
                    breg[q] = *(const f16x8*)(Bt +
                        ((size_t)(par2 * COUT + cbase + o) * KTOT +
                         tap2 * CIN + kh2 * CINS) + sl * 8);
                }
            }
            // compute stage s
            const int iu = (tap >> 1) + pi, iv = (tap & 1) + pj;
            const int delta = (iu - 1) * HIN + (iv - 1);
            int rp[R]; bool ok[R];
            #pragma unroll
            for (int r = 0; r < R; ++r) {
                int t = posl[r] + delta;
                rp[r] = min(max(t, 0), AROWS - 1);
                ok[r] = okr[r][iu] && okc[r][iv];
            }
            const _Float16* Bl = &lds[AH + buf * BH];
            #pragma unroll
            for (int cc = 0; cc < NSTEPS; ++cc) {
                const int slB = cc * 4 + kg;
                const int slA = kh * SLB + slB;
                f16x8 b[CF];
                #pragma unroll
                for (int f = 0; f < CF; ++f)
                    b[f] = *(const f16x8*)(&Bl[(f * 16 + coll) * CINS +
                                               ((slB ^ (coll & 7)) * 8)]);
                f16x8 a[R];
                #pragma unroll
                for (int r = 0; r < R; ++r) {
                    f16x8 v = *(const f16x8*)(&lds[rp[r] * CIN +
                                                   ((slA ^ (rp[r] & 7)) * 8)]);
                    a[r] = ok[r] ? v : (f16x8){0, 0, 0, 0, 0, 0, 0, 0};
                }
                #pragma unroll
                for (int r = 0; r < R; ++r)
                    #pragma unroll
                    for (int f = 0; f < CF; ++f)
                        acc[r][f] = __builtin_amdgcn_mfma_f32_16x16x32_f16(
                            a[r], b[f], acc[r][f], 0, 0, 0);
            }
            // write-late into the other buffer, one barrier per stage
            if (s + 1 < NST) {
                #pragma unroll
                for (int q = 0; q < NSB; ++q) {
                    int i = tid + q * T;
                    int o = i / SLB, sl = i % SLB;
                    *(f16x8*)(&lds[AH + ((s + 1) & 1) * BH + o * CINS +
                                   ((sl ^ (o & 7)) * 8)]) = breg[q];
                }
                __syncthreads();
            }
        }

        // ---- epilogue for this parity ----
        #pragma unroll
        for (int r = 0; r < R; ++r) {
            #pragma unroll
            for (int g = 0; g < 4; ++g) {
                int p = posbase + r * 16 + kg * 4 + g;
                int ni = p >> (2 * LOGH);
                int rem = p & (HH - 1);
                int a2 = rem >> LOGH, b2 = rem & (HIN - 1);
                size_t ob = (((size_t)(n0 + ni) * OH + 2 * a2 + pi + OB) * OH +
                             2 * b2 + pj + OB) * COUT;
                #pragma unroll
                for (int f = 0; f < CF; ++f) {
                    float v = acc[r][f][g];
                    v = v > 0.f ? v : 0.f;
                    Y[ob + cbase + f * 16 + coll] = __float2half(v);
                }
            }
        }
    }
}

// ---------------- zero the 1-wide border ring of padded x3 -------------------
__global__ __launch_bounds__(256) void pad_zero(__half* __restrict__ Xp) {
    int n = blockIdx.x;
    __half* base = Xp + (size_t)n * 34 * 34 * 32;
    for (int w = threadIdx.x; w < 132 * 4; w += 256) {
        int posi = w >> 2, q = w & 3;
        int r, s;
        if (posi < 68) { r = (posi < 34) ? 0 : 33; s = posi % 34; }
        else { int e = posi - 68; r = 1 + (e >> 1); s = (e & 1) ? 33 : 0; }
        *(f16x8*)(base + ((size_t)r * 34 + s) * 32 + q * 8) = (f16x8){0, 0, 0, 0, 0, 0, 0, 0};
    }
}

// ---------------- conv4: padded 34x34x32 -> 64x64x1, fp32 out ----------------
__global__ __launch_bounds__(256) void conv4_kernel2(
    const __half* __restrict__ Xp, const __half* __restrict__ Wh,
    const float* __restrict__ bias, float* __restrict__ out) {
    int n = blockIdx.x;
    int t = threadIdx.x;
    int b = t & 31;
    int a = (blockIdx.y << 3) + (t >> 5);
    const __half* Xn = Xp + (size_t)n * 34 * 34 * 32;
    const f16x2* W2 = (const f16x2*)Wh;
    float a00 = 0.f, a01 = 0.f, a10 = 0.f, a11 = 0.f;
    #pragma unroll
    for (int hf = 0; hf < 2; ++hf) {
        f16x2 xw[9][8];
        #pragma unroll
        for (int u = 0; u < 3; ++u)
            #pragma unroll
            for (int v = 0; v < 3; ++v) {
                const f16x8* p = (const f16x8*)(Xn + ((size_t)(a + u) * 34 + (b + v)) * 32 + hf * 16);
                f16x8 lo = p[0], hi = p[1];
                #pragma unroll
                for (int e = 0; e < 4; ++e) {
                    xw[u * 3 + v][e]     = (f16x2){lo[2 * e], lo[2 * e + 1]};
                    xw[u * 3 + v][e + 4] = (f16x2){hi[2 * e], hi[2 * e + 1]};
                }
            }
        #pragma unroll
        for (int pi = 0; pi < 2; ++pi)
            #pragma unroll
            for (int pj = 0; pj < 2; ++pj) {
                float acc = pi ? (pj ? a11 : a10) : (pj ? a01 : a00);
                #pragma unroll
                for (int t1 = 0; t1 < 2; ++t1)
                    #pragma unroll
                    for (int t2 = 0; t2 < 2; ++t2) {
                        int pos = (pi + t1) * 3 + (pj + t2);
                        const f16x2* wrow = W2 + ((pi + 2 * t1) * 4 + (pj + 2 * t2)) * 16 + hf * 8;
                        #pragma unroll
                        for (int e = 0; e < 8; ++e)
                            acc = dot2f(xw[pos][e], wrow[e], acc);
                    }
                if (pi) { if (pj) a11 = acc; else a10 = acc; }
                else    { if (pj) a01 = acc; else a00 = acc; }
            }
    }
    float bv = bias[0];
    out[((size_t)n * 64 + 2 * a + 0) * 64 + 2 * b + 0] = a00 + bv;
    out[((size_t)n * 64 + 2 * a + 0) * 64 + 2 * b + 1] = a01 + bv;
    out[((size_t)n * 64 + 2 * a + 1) * 64 + 2 * b + 0] = a10 + bv;
    out[((size_t)n * 64 + 2 * a + 1) * 64 + 2 * b + 1] = a11 + bv;
}

// ---------------- launch -----------------------------------------------------
extern "C" void kernel_launch(void* const* d_in, const int* in_sizes, int n_in,
                              void* d_out, int out_size, void* d_ws, size_t ws_size,
                              hipStream_t stream) {
    const float* angles   = (const float*)d_in[0];
    const float* item_rep = (const float*)d_in[1];
    const float* W        = (const float*)d_in[2];
    const float* bfc      = (const float*)d_in[3];
    const float* k1       = (const float*)d_in[4];
    const float* b1       = (const float*)d_in[5];
    const float* k2       = (const float*)d_in[6];
    const float* b2       = (const float*)d_in[7];
    const float* k3       = (const float*)d_in[8];
    const float* b3       = (const float*)d_in[9];
    const float* k4       = (const float*)d_in[10];
    const float* b4       = (const float*)d_in[11];

    char* ws = (char*)d_ws;
    float*  Ctab  = (float*)(ws + 0);                 //  32 KB
    __half* itemh = (__half*)(ws + 32768);            //   2 MB
    __half* Bt1   = (__half*)(ws + 2129920);          //   1 MB
    __half* Bt2   = (__half*)(ws + 3178496);          // 256 KB
    __half* Bt3   = (__half*)(ws + 3440640);          //  64 KB
    __half* Kh4   = (__half*)(ws + 3506176);          //   1 KB
    __half* x0    = (__half*)(ws + 4194304);          //  16 MB -> 20,971,520
    __half* x1    = (__half*)(ws + 20971520);         //  32 MB -> 54,525,952
    __half* x3p   = (__half*)(ws + 4194304);          // 151.5 MB -> 155,713,536
    __half* Wtfc  = (__half*)(ws + 121634816);        //   4 MB (inside x3p, dead by conv3)
    __half* x2    = (__half*)(ws + 155713536);        //  64 MB -> 222,822,400
    float*  out   = (float*)d_out;

    coef_kernel<<<1, 512, 0, stream>>>(Ctab);
    wigner_kernel<<<NBATCH, 64, 0, stream>>>(angles, item_rep, Ctab, itemh);
    fcw_prep2<<<dim3(KPAD / 64, HID / 64), 256, 0, stream>>>(W, Wtfc);
    convw_prep<256, 128><<<16, 256, 0, stream>>>(k1, Bt1);
    convw_prep<128, 64><<<16, 256, 0, stream>>>(k2, Bt2);
    convw_prep<64, 32><<<16, 256, 0, stream>>>(k3, Bt3);
    conv4w_prep<<<2, 256, 0, stream>>>(k4, Kh4);

    // FC: 2048x512 @ 512x4096 -> x0
    fc_mfma<<<dim3(16, 32), 256, 0, stream>>>(itemh, Wtfc, bfc, x0);
    // conv1: 4x4x256 -> 8x8x128  (R=1, CF=4, y=2 slices, k-split B stages)
    //        LDS = 32KB A + 2x16KB B = 64KB
    convt_lds3<256, 128, 4, 1, 2, 4, 4, 2, 8, 0><<<dim3(512, 2), 256, 0, stream>>>(x0, Bt1, b1, x1);
    // conv2: 8x8x128 -> 16x16x64 (R=2, CF=4) LDS = 32+32 = 64KB
    convt_lds3<128, 64, 8, 2, 3, 4, 4, 1, 16, 0><<<dim3(1024, 1), 256, 0, stream>>>(x1, Bt2, b2, x2);
    // zero x3p border ring, then conv3 writes the 32x32 interior at +1
    pad_zero<<<NBATCH, 256, 0, stream>>>(x3p);
    // conv3: 16x16x64 -> (34x34 padded)x32 (R=4, CF=2) LDS = 32+8 = 40KB
    convt_lds3<64, 32, 16, 4, 4, 2, 4, 1, 34, 1><<<dim3(2048, 1), 256, 0, stream>>>(x2, Bt3, b3, x3p);
    // conv4: padded 34x34x32 -> 64x64x1 (fp32 out)
    conv4_kernel2<<<dim3(NBATCH, 4), 256, 0, stream>>>(x3p, Kh4, b4, out);
}